// Round 1
// baseline (802.958 us; speedup 1.0000x reference)
//
#include <hip/hip_runtime.h>

typedef _Float16 f16x8 __attribute__((ext_vector_type(8)));
typedef float    f32x4 __attribute__((ext_vector_type(4)));

#define NROWS   262144
#define DIN     128
#define DOUT    256
#define RPB     64                   // rows per block-chunk (4 waves x 16)
#define NCHUNKS (NROWS / RPB)        // 4096
#define GRID    1024

// lane-swizzle XOR butterfly within 16-lane groups (BitMode: and=0x1F, xor in bits 10+)
#define SWZ_F(x, pat) __int_as_float(__builtin_amdgcn_ds_swizzle(__float_as_int(x), (pat)))
#define SWZ_I(x, pat) __builtin_amdgcn_ds_swizzle((x), (pat))

__global__ __launch_bounds__(256, 2)
void attentive_kernel(const float* __restrict__ A,
                      const float* __restrict__ priors,
                      const float* __restrict__ W,
                      const float* __restrict__ gamma,
                      const float* __restrict__ beta,
                      const float* __restrict__ mmean,
                      const float* __restrict__ mvar,
                      float* __restrict__ out)
{
    // W (BN inv-scale folded) as fp16 in MFMA-B-frag-ready order:
    // half index = ((t*4+q)*64 + lane)*8 + j
    //   col n = 16*t + (lane&15), k = 32*q + 8*(lane>>4) + j
    __shared__ _Float16 wlds[DIN * DOUT];   // exactly 64 KiB

    const int tid = threadIdx.x;

    // ---- stage W' = W * inv, one column per thread (coalesced reads) ----
    {
        const int n = tid;
        const float inv = gamma[n] / sqrtf(mvar[n] + 1e-3f);
        const int t = n >> 4, nl0 = n & 15;
        #pragma unroll 8
        for (int k = 0; k < DIN; ++k) {
            const int q = k >> 5, qd = (k >> 3) & 3, j = k & 7;
            const int idx = (((((t << 2) + q) << 6) + (qd << 4) + nl0) << 3) + j;
            wlds[idx] = (_Float16)(W[k * DOUT + n] * inv);
        }
    }
    __syncthreads();

    const int lane = tid & 63;
    const int wv   = tid >> 6;
    const int nl   = lane & 15;
    const int quad = lane >> 4;

    // ---- per-lane BN offset b2 for this lane's 16 columns (c = 16t + nl) ----
    float b2r[16];
    #pragma unroll
    for (int t = 0; t < 16; ++t) {
        const int c = (t << 4) + nl;
        const float inv = gamma[c] / sqrtf(mvar[c] + 1e-3f);
        b2r[t] = beta[c] - mmean[c] * inv;
    }

    for (int chunk = blockIdx.x; chunk < NCHUNKS; chunk += gridDim.x) {
        const int r0 = chunk * RPB + wv * 16;

        // ---- A fragments: A[m=nl][k = 32q + 8*quad + j], fp32 -> fp16 ----
        f16x8 af[4];
        const float* arow = A + (size_t)(r0 + nl) * DIN + (quad << 3);
        #pragma unroll
        for (int q = 0; q < 4; ++q) {
            const float4 lo = *(const float4*)(arow + (q << 5));
            const float4 hi = *(const float4*)(arow + (q << 5) + 4);
            f16x8 v;
            v[0] = (_Float16)lo.x; v[1] = (_Float16)lo.y;
            v[2] = (_Float16)lo.z; v[3] = (_Float16)lo.w;
            v[4] = (_Float16)hi.x; v[5] = (_Float16)hi.y;
            v[6] = (_Float16)hi.z; v[7] = (_Float16)hi.w;
            af[q] = v;
        }

        // ---- GEMM: acc = A @ W'  (C-layout: col=16t+nl, row=r0+4*quad+j) ----
        f32x4 acc[16];
        #pragma unroll
        for (int t = 0; t < 16; ++t) {
            f32x4 c = {0.f, 0.f, 0.f, 0.f};
            #pragma unroll
            for (int q = 0; q < 4; ++q) {
                const f16x8 bf = *(const f16x8*)&wlds[((((t << 2) + q) << 6) + lane) << 3];
                c = __builtin_amdgcn_mfma_f32_16x16x32_f16(af[q], bf, c, 0, 0, 0);
            }
            acc[t] = c;
        }

        // ---- z = (acc + b2) * priors ----
        const int rb = r0 + (quad << 2);
        #pragma unroll
        for (int t = 0; t < 16; ++t) {
            const int c = (t << 4) + nl;
            #pragma unroll
            for (int j = 0; j < 4; ++j) {
                const float p = priors[(rb + j) * DOUT + c];
                acc[t][j] = (acc[t][j] + b2r[t]) * p;
            }
        }

        // ---- sparsemax: Michelot fixed-point on tau ----
        // tau_{t+1} = (sum_{z>tau_t} z - 1)/|{z>tau_t}| ; tau monotone non-decreasing,
        // active set shrinks monotonically -> finite exact convergence (k stabilizes).
        float tau[4] = {-3.0e38f, -3.0e38f, -3.0e38f, -3.0e38f};
        int   kp[4]  = {-1, -1, -1, -1};
        for (int it = 0; it < 64; ++it) {
            float S[4] = {0.f, 0.f, 0.f, 0.f};
            int   K[4] = {0, 0, 0, 0};
            #pragma unroll
            for (int t = 0; t < 16; ++t) {
                #pragma unroll
                for (int j = 0; j < 4; ++j) {
                    const float z = acc[t][j];
                    const bool b = z > tau[j];
                    S[j] += b ? z : 0.0f;
                    K[j] += b ? 1 : 0;
                }
            }
            // reduce (S, K) across the 16 lanes of each quad-group
            #pragma unroll
            for (int j = 0; j < 4; ++j) {
                S[j] += SWZ_F(S[j], 0x041F); K[j] += SWZ_I(K[j], 0x041F);
                S[j] += SWZ_F(S[j], 0x081F); K[j] += SWZ_I(K[j], 0x081F);
                S[j] += SWZ_F(S[j], 0x101F); K[j] += SWZ_I(K[j], 0x101F);
                S[j] += SWZ_F(S[j], 0x201F); K[j] += SWZ_I(K[j], 0x201F);
            }
            bool conv = true;
            #pragma unroll
            for (int j = 0; j < 4; ++j) {
                tau[j] = (S[j] - 1.0f) * __builtin_amdgcn_rcpf((float)K[j]);
                conv = conv && (K[j] == kp[j]);
                kp[j] = K[j];
            }
            if (__all(conv)) break;
        }

        // ---- epilogue: out = max(z - tau, 0) ----
        #pragma unroll
        for (int t = 0; t < 16; ++t) {
            const int c = (t << 4) + nl;
            #pragma unroll
            for (int j = 0; j < 4; ++j) {
                out[(rb + j) * DOUT + c] = fmaxf(acc[t][j] - tau[j], 0.0f);
            }
        }
    }
}

extern "C" void kernel_launch(void* const* d_in, const int* in_sizes, int n_in,
                              void* d_out, int out_size, void* d_ws, size_t ws_size,
                              hipStream_t stream) {
    const float* inputs = (const float*)d_in[0];
    const float* priors = (const float*)d_in[1];
    const float* W      = (const float*)d_in[2];
    const float* gam    = (const float*)d_in[3];
    const float* bet    = (const float*)d_in[4];
    const float* mmean  = (const float*)d_in[5];
    const float* mvar   = (const float*)d_in[6];
    float* outp = (float*)d_out;
    (void)in_sizes; (void)n_in; (void)out_size; (void)d_ws; (void)ws_size;

    hipLaunchKernelGGL(attentive_kernel, dim3(GRID), dim3(256), 0, stream,
                       inputs, priors, W, gam, bet, mmean, mvar, outp);
}

// Round 2
// 718.048 us; speedup vs baseline: 1.1183x; 1.1183x over previous
//
#include <hip/hip_runtime.h>

typedef _Float16 f16x8 __attribute__((ext_vector_type(8)));
typedef float    f32x4 __attribute__((ext_vector_type(4)));

#define NROWS   262144
#define DIN     128
#define DOUT    256
#define NCHUNKS (NROWS / 64)          // 4096 blocks, 64 rows each (4 waves x 16)
#define WS_NEED (DIN * DOUT * 2 + DOUT * 4)   // W' fp16 + b2 table

#define SWZ_F(x, pat) __int_as_float(__builtin_amdgcn_ds_swizzle(__float_as_int(x), (pat)))
#define SWZ_I(x, pat) __builtin_amdgcn_ds_swizzle((x), (pat))

// ---------- prep: W' = W * gamma/rsqrt(var+eps) in fp16 B-frag order; b2 table ----------
__global__ void prep_kernel(const float* __restrict__ W,
                            const float* __restrict__ gamma,
                            const float* __restrict__ beta,
                            const float* __restrict__ mmean,
                            const float* __restrict__ mvar,
                            _Float16* __restrict__ wq,
                            float* __restrict__ b2tab)
{
    const int tid  = blockIdx.x * 256 + threadIdx.x;    // 0..4095 = (t, q, lane)
    const int t    = tid >> 8;
    const int q    = (tid >> 6) & 3;
    const int lane = tid & 63;
    const int n    = 16 * t + (lane & 15);
    const int k0   = 32 * q + 8 * (lane >> 4);
    const float inv = gamma[n] / sqrtf(mvar[n] + 1e-3f);
    f16x8 v;
    #pragma unroll
    for (int j = 0; j < 8; ++j)
        v[j] = (_Float16)(W[(k0 + j) * DOUT + n] * inv);
    *(f16x8*)(wq + (size_t)tid * 8) = v;               // frag half-index = ((t*4+q)*64+lane)*8+j
    if (blockIdx.x == 0) {
        const int c = threadIdx.x;
        const float invc = gamma[c] / sqrtf(mvar[c] + 1e-3f);
        b2tab[c] = beta[c] - mmean[c] * invc;
    }
}

// ---------- main: GEMM(fp16 MFMA) -> LDS transpose -> vectorized BN+prior+sparsemax ----------
__global__ __launch_bounds__(256, 3)
void attentive_main(const float* __restrict__ A,
                    const float* __restrict__ priors,
                    const _Float16* __restrict__ wq,
                    const float* __restrict__ b2tab,
                    float* __restrict__ out)
{
    __shared__ float tbuf[4][8 * 256];     // 8 rows x 256 cols per wave, XOR-swizzled, 32 KiB

    const int tid  = threadIdx.x;
    const int lane = tid & 63;
    const int wv   = tid >> 6;
    const int nl   = lane & 15;            // MFMA C-layout col-low / A row
    const int quad = lane >> 4;
    const int lo   = lane & 7;             // epilogue: col-group
    const int hi   = lane >> 3;            // epilogue: row within 8-row pass
    const int r0   = blockIdx.x * 64 + wv * 16;

    // ---- A fragments: A[m=nl][k = 32q + 8*quad + j], fp32 -> fp16 ----
    f16x8 af[4];
    {
        const float* arow = A + (size_t)(r0 + nl) * DIN + (quad << 3);
        #pragma unroll
        for (int q = 0; q < 4; ++q) {
            const float4 vlo = *(const float4*)(arow + (q << 5));
            const float4 vhi = *(const float4*)(arow + (q << 5) + 4);
            f16x8 v;
            v[0] = (_Float16)vlo.x; v[1] = (_Float16)vlo.y;
            v[2] = (_Float16)vlo.z; v[3] = (_Float16)vlo.w;
            v[4] = (_Float16)vhi.x; v[5] = (_Float16)vhi.y;
            v[6] = (_Float16)vhi.z; v[7] = (_Float16)vhi.w;
            af[q] = v;
        }
    }

    // ---- GEMM: acc = A @ W'  (C-layout: col=16t+nl, row=4*quad+j) ----
    f32x4 acc[16];
    #pragma unroll
    for (int t = 0; t < 16; ++t) {
        f32x4 c = {0.f, 0.f, 0.f, 0.f};
        #pragma unroll
        for (int q = 0; q < 4; ++q) {
            const f16x8 bf = *(const f16x8*)(wq + ((size_t)((t << 2) + q) * 64 + lane) * 8);
            c = __builtin_amdgcn_mfma_f32_16x16x32_f16(af[q], bf, c, 0, 0, 0);
        }
        acc[t] = c;
    }

    float* buf = &tbuf[wv][0];

    // ---- two passes of 8 rows: transpose via swizzled LDS, then vector epilogue ----
    #pragma unroll 1
    for (int p = 0; p < 2; ++p) {
        // write phase: lanes whose rows fall in this pass (quad>>1 == p)
        if ((quad >> 1) == p) {
            #pragma unroll
            for (int t = 0; t < 16; ++t) {
                const int col = (t << 4) + nl;
                const int g   = col >> 2;
                const int off = col & 3;
                #pragma unroll
                for (int j = 0; j < 4; ++j) {
                    const int br = ((quad & 1) << 2) + j;    // buffer row 0..7
                    const int gp = g ^ br;                   // XOR swizzle (conflict-free)
                    buf[br * 256 + (gp << 2) + off] = acc[t][j];
                }
            }
        }
        __syncthreads();

        // read phase: lane owns row hi, cols 32c + 4*lo (full 128B line segments)
        const int rg = r0 + 8 * p + hi;                      // global row
        f32x4 zt[8];
        #pragma unroll
        for (int c = 0; c < 8; ++c) {
            const int g  = (c << 3) + lo;
            const int gp = g ^ hi;
            f32x4 v = *(const f32x4*)&buf[hi * 256 + (gp << 2)];
            const int colb = (c << 5) + (lo << 2);
            const float4 b2 = *(const float4*)(b2tab + colb);
            const float4 pv = *(const float4*)(priors + (size_t)rg * DOUT + colb);
            zt[c][0] = (v[0] + b2.x) * pv.x;
            zt[c][1] = (v[1] + b2.y) * pv.y;
            zt[c][2] = (v[2] + b2.z) * pv.z;
            zt[c][3] = (v[3] + b2.w) * pv.w;
        }

        // ---- sparsemax (Michelot fixed point); reduce across lo (xor 1,2,4) ----
        float tau = -3.0e38f;
        float kprev = -1.0f;
        for (int it = 0; it < 64; ++it) {
            float S = 0.0f, K = 0.0f;
            #pragma unroll
            for (int c = 0; c < 8; ++c) {
                #pragma unroll
                for (int j = 0; j < 4; ++j) {
                    const float z = zt[c][j];
                    const bool b = z > tau;
                    S += b ? z : 0.0f;
                    K += b ? 1.0f : 0.0f;
                }
            }
            S += SWZ_F(S, 0x041F); K += SWZ_F(K, 0x041F);
            S += SWZ_F(S, 0x081F); K += SWZ_F(K, 0x081F);
            S += SWZ_F(S, 0x101F); K += SWZ_F(K, 0x101F);
            tau = (S - 1.0f) * __builtin_amdgcn_rcpf(K);
            const bool conv = (K == kprev);
            kprev = K;
            if (__all(conv)) break;
        }

        // ---- store: out = max(z - tau, 0), float4, full-line segments ----
        #pragma unroll
        for (int c = 0; c < 8; ++c) {
            const int colb = (c << 5) + (lo << 2);
            float4 o;
            o.x = fmaxf(zt[c][0] - tau, 0.0f);
            o.y = fmaxf(zt[c][1] - tau, 0.0f);
            o.z = fmaxf(zt[c][2] - tau, 0.0f);
            o.w = fmaxf(zt[c][3] - tau, 0.0f);
            *(float4*)(out + (size_t)rg * DOUT + colb) = o;
        }
        __syncthreads();
    }
}

// ---------- fallback (round-1 kernel, proven correct) for tiny ws ----------
__global__ __launch_bounds__(256, 2)
void attentive_fallback(const float* __restrict__ A,
                        const float* __restrict__ priors,
                        const float* __restrict__ W,
                        const float* __restrict__ gamma,
                        const float* __restrict__ beta,
                        const float* __restrict__ mmean,
                        const float* __restrict__ mvar,
                        float* __restrict__ out)
{
    __shared__ _Float16 wlds[DIN * DOUT];
    const int tid = threadIdx.x;
    {
        const int n = tid;
        const float inv = gamma[n] / sqrtf(mvar[n] + 1e-3f);
        const int t = n >> 4, nl0 = n & 15;
        #pragma unroll 8
        for (int k = 0; k < DIN; ++k) {
            const int q = k >> 5, qd = (k >> 3) & 3, j = k & 7;
            const int idx = (((((t << 2) + q) << 6) + (qd << 4) + nl0) << 3) + j;
            wlds[idx] = (_Float16)(W[k * DOUT + n] * inv);
        }
    }
    __syncthreads();

    const int lane = tid & 63, wv = tid >> 6;
    const int nl = lane & 15, quad = lane >> 4;

    float b2r[16];
    #pragma unroll
    for (int t = 0; t < 16; ++t) {
        const int c = (t << 4) + nl;
        const float inv = gamma[c] / sqrtf(mvar[c] + 1e-3f);
        b2r[t] = beta[c] - mmean[c] * inv;
    }

    for (int chunk = blockIdx.x; chunk < NCHUNKS; chunk += gridDim.x) {
        const int r0 = chunk * 64 + wv * 16;
        f16x8 af[4];
        const float* arow = A + (size_t)(r0 + nl) * DIN + (quad << 3);
        #pragma unroll
        for (int q = 0; q < 4; ++q) {
            const float4 vlo = *(const float4*)(arow + (q << 5));
            const float4 vhi = *(const float4*)(arow + (q << 5) + 4);
            f16x8 v;
            v[0] = (_Float16)vlo.x; v[1] = (_Float16)vlo.y;
            v[2] = (_Float16)vlo.z; v[3] = (_Float16)vlo.w;
            v[4] = (_Float16)vhi.x; v[5] = (_Float16)vhi.y;
            v[6] = (_Float16)vhi.z; v[7] = (_Float16)vhi.w;
            af[q] = v;
        }
        f32x4 acc[16];
        #pragma unroll
        for (int t = 0; t < 16; ++t) {
            f32x4 c = {0.f, 0.f, 0.f, 0.f};
            #pragma unroll
            for (int q = 0; q < 4; ++q) {
                const f16x8 bf = *(const f16x8*)&wlds[((((t << 2) + q) << 6) + lane) << 3];
                c = __builtin_amdgcn_mfma_f32_16x16x32_f16(af[q], bf, c, 0, 0, 0);
            }
            acc[t] = c;
        }
        const int rb = r0 + (quad << 2);
        #pragma unroll
        for (int t = 0; t < 16; ++t) {
            const int c = (t << 4) + nl;
            #pragma unroll
            for (int j = 0; j < 4; ++j) {
                const float p = priors[(size_t)(rb + j) * DOUT + c];
                acc[t][j] = (acc[t][j] + b2r[t]) * p;
            }
        }
        float tau[4] = {-3.0e38f, -3.0e38f, -3.0e38f, -3.0e38f};
        int   kp[4]  = {-1, -1, -1, -1};
        for (int it = 0; it < 64; ++it) {
            float S[4] = {0.f, 0.f, 0.f, 0.f};
            int   K[4] = {0, 0, 0, 0};
            #pragma unroll
            for (int t = 0; t < 16; ++t) {
                #pragma unroll
                for (int j = 0; j < 4; ++j) {
                    const float z = acc[t][j];
                    const bool b = z > tau[j];
                    S[j] += b ? z : 0.0f;
                    K[j] += b ? 1 : 0;
                }
            }
            #pragma unroll
            for (int j = 0; j < 4; ++j) {
                S[j] += SWZ_F(S[j], 0x041F); K[j] += SWZ_I(K[j], 0x041F);
                S[j] += SWZ_F(S[j], 0x081F); K[j] += SWZ_I(K[j], 0x081F);
                S[j] += SWZ_F(S[j], 0x101F); K[j] += SWZ_I(K[j], 0x101F);
                S[j] += SWZ_F(S[j], 0x201F); K[j] += SWZ_I(K[j], 0x201F);
            }
            bool conv = true;
            #pragma unroll
            for (int j = 0; j < 4; ++j) {
                tau[j] = (S[j] - 1.0f) * __builtin_amdgcn_rcpf((float)K[j]);
                conv = conv && (K[j] == kp[j]);
                kp[j] = K[j];
            }
            if (__all(conv)) break;
        }
        #pragma unroll
        for (int t = 0; t < 16; ++t) {
            const int c = (t << 4) + nl;
            #pragma unroll
            for (int j = 0; j < 4; ++j)
                out[(size_t)(rb + j) * DOUT + c] = fmaxf(acc[t][j] - tau[j], 0.0f);
        }
    }
}

extern "C" void kernel_launch(void* const* d_in, const int* in_sizes, int n_in,
                              void* d_out, int out_size, void* d_ws, size_t ws_size,
                              hipStream_t stream) {
    const float* inputs = (const float*)d_in[0];
    const float* priors = (const float*)d_in[1];
    const float* W      = (const float*)d_in[2];
    const float* gam    = (const float*)d_in[3];
    const float* bet    = (const float*)d_in[4];
    const float* mmean  = (const float*)d_in[5];
    const float* mvar   = (const float*)d_in[6];
    float* outp = (float*)d_out;
    (void)in_sizes; (void)n_in; (void)out_size;

    if (ws_size >= (size_t)WS_NEED) {
        _Float16* wq    = (_Float16*)d_ws;
        float*    b2tab = (float*)((char*)d_ws + DIN * DOUT * 2);
        hipLaunchKernelGGL(prep_kernel, dim3(16), dim3(256), 0, stream,
                           W, gam, bet, mmean, mvar, wq, b2tab);
        hipLaunchKernelGGL(attentive_main, dim3(NCHUNKS), dim3(256), 0, stream,
                           inputs, priors, wq, b2tab, outp);
    } else {
        hipLaunchKernelGGL(attentive_fallback, dim3(1024), dim3(256), 0, stream,
                           inputs, priors, W, gam, bet, mmean, mvar, outp);
    }
}

// Round 4
// 614.356 us; speedup vs baseline: 1.3070x; 1.1688x over previous
//
#include <hip/hip_runtime.h>

typedef _Float16 f16x8 __attribute__((ext_vector_type(8)));
typedef float    f32x4 __attribute__((ext_vector_type(4)));

#define NROWS   262144
#define DIN     128
#define DOUT    256
#define NCHUNKS (NROWS / 64)          // 4096 blocks, 64 rows each (4 waves x 16)
#define WS_NEED (DIN * DOUT * 2 + DOUT * 4)   // W' fp16 + b2 table

#define SWZ_F(x, pat) __int_as_float(__builtin_amdgcn_ds_swizzle(__float_as_int(x), (pat)))
#define SWZ_I(x, pat) __builtin_amdgcn_ds_swizzle((x), (pat))

// DPP cross-lane add (VALU pipe, ~4cyc — replaces LDS-pipe ds_swizzle)
template<int CTRL>
__device__ __forceinline__ float dpp_addf(float x) {
    const int y = __builtin_amdgcn_mov_dpp(__float_as_int(x), CTRL, 0xF, 0xF, true);
    return x + __int_as_float(y);
}
#define DPP_XOR1 0xB1   // quad_perm [1,0,3,2]
#define DPP_XOR2 0x4E   // quad_perm [2,3,0,1]
#define DPP_HMIR 0x141  // row_half_mirror: swaps quads within 8-lane group

// ---------- prep: W' = W * gamma/rsqrt(var+eps) in fp16 B-frag order; b2 table ----------
__global__ void prep_kernel(const float* __restrict__ W,
                            const float* __restrict__ gamma,
                            const float* __restrict__ beta,
                            const float* __restrict__ mmean,
                            const float* __restrict__ mvar,
                            _Float16* __restrict__ wq,
                            float* __restrict__ b2tab)
{
    const int tid  = blockIdx.x * 256 + threadIdx.x;    // 0..4095 = (t, q, lane)
    const int t    = tid >> 8;
    const int q    = (tid >> 6) & 3;
    const int lane = tid & 63;
    const int n    = 16 * t + (lane & 15);
    const int k0   = 32 * q + 8 * (lane >> 4);
    const float inv = gamma[n] / sqrtf(mvar[n] + 1e-3f);
    f16x8 v;
    #pragma unroll
    for (int j = 0; j < 8; ++j)
        v[j] = (_Float16)(W[(k0 + j) * DOUT + n] * inv);
    *(f16x8*)(wq + (size_t)tid * 8) = v;               // frag half-index = ((t*4+q)*64+lane)*8+j
    if (blockIdx.x == 0) {
        const int c = threadIdx.x;
        const float invc = gamma[c] / sqrtf(mvar[c] + 1e-3f);
        b2tab[c] = beta[c] - mmean[c] * invc;
    }
}

// Michelot fixed point on tau; zt = 8 x f32x4 (32 cols of one row per lane),
// row shared by the 8 lanes with equal (lane>>3). DPP tree-reduce over those 8.
__device__ __forceinline__ float michelot(const f32x4* zt) {
    float tau = -3.0e38f, kprev = -1.0f;
    for (int it = 0; it < 64; ++it) {
        float S = 0.0f, K = 0.0f;
        #pragma unroll
        for (int c = 0; c < 8; ++c) {
            #pragma unroll
            for (int j = 0; j < 4; ++j) {
                const float z = zt[c][j];
                const bool b = z > tau;
                S += b ? z : 0.0f;
                K += b ? 1.0f : 0.0f;
            }
        }
        S = dpp_addf<DPP_XOR1>(S); K = dpp_addf<DPP_XOR1>(K);
        S = dpp_addf<DPP_XOR2>(S); K = dpp_addf<DPP_XOR2>(K);
        S = dpp_addf<DPP_HMIR>(S); K = dpp_addf<DPP_HMIR>(K);
        tau = (S - 1.0f) * __builtin_amdgcn_rcpf(K);
        const bool conv = (K == kprev);
        kprev = K;
        if (__all(conv)) break;
    }
    return tau;
}

// ---------- main: GEMM(fp16 MFMA) -> per-wave LDS transpose (no barriers) ----------
__global__ __launch_bounds__(256, 4)
void attentive_main(const float* __restrict__ A,
                    const float* __restrict__ priors,
                    const _Float16* __restrict__ wq,
                    const float* __restrict__ b2tab,
                    float* __restrict__ out)
{
    __shared__ float tbuf[4][8 * 256];     // 8 KiB per wave, XOR-swizzled

    const int tid  = threadIdx.x;
    const int lane = tid & 63;
    const int wv   = tid >> 6;
    const int nl   = lane & 15;            // MFMA C-layout col-low / A row
    const int quad = lane >> 4;
    const int lo   = lane & 7;             // epilogue: col-group
    const int hi   = lane >> 3;            // epilogue: row within 8-row pass
    const int r0   = blockIdx.x * 64 + wv * 16;
    const int cb   = lo << 2;              // 16B offset within each 128B col-group

    // ---- A fragments: A[m=nl][k = 32q + 8*quad + j], fp32 -> fp16 ----
    f16x8 af[4];
    {
        const float* arow = A + (size_t)(r0 + nl) * DIN + (quad << 3);
        #pragma unroll
        for (int q = 0; q < 4; ++q) {
            const f32x4 vlo = *(const f32x4*)(arow + (q << 5));
            const f32x4 vhi = *(const f32x4*)(arow + (q << 5) + 4);
            f16x8 v;
            v[0] = (_Float16)vlo[0]; v[1] = (_Float16)vlo[1];
            v[2] = (_Float16)vlo[2]; v[3] = (_Float16)vlo[3];
            v[4] = (_Float16)vhi[0]; v[5] = (_Float16)vhi[1];
            v[6] = (_Float16)vhi[2]; v[7] = (_Float16)vhi[3];
            af[q] = v;
        }
    }

    // ---- GEMM: acc = A @ W'  (C-layout: col=16t+nl, row=4*quad+j) ----
    f32x4 acc[16];
    #pragma unroll
    for (int t = 0; t < 16; ++t) {
        f32x4 c = {0.f, 0.f, 0.f, 0.f};
        #pragma unroll
        for (int q = 0; q < 4; ++q) {
            const f16x8 bf = *(const f16x8*)(wq + ((size_t)((t << 2) + q) * 64 + lane) * 8);
            c = __builtin_amdgcn_mfma_f32_16x16x32_f16(af[q], bf, c, 0, 0, 0);
        }
        acc[t] = c;
    }

    float* buf = &tbuf[wv][0];

    // ---- issue pass-0 priors loads (overlap with LDS transpose) ----
    f32x4 pv0[8];
    {
        const float* pr = priors + (size_t)(r0 + hi) * DOUT;
        #pragma unroll
        for (int c = 0; c < 8; ++c)
            pv0[c] = __builtin_nontemporal_load((const f32x4*)(pr + (c << 5) + cb));
    }

    // ---- pass-0 LDS writes: rows 0..7 (lanes quad 0,1) ----
    if (quad < 2) {
        #pragma unroll
        for (int t = 0; t < 16; ++t) {
            const int col = (t << 4) + nl;
            const int g = col >> 2, off = col & 3;
            #pragma unroll
            for (int j = 0; j < 4; ++j) {
                const int br = ((quad & 1) << 2) + j;
                buf[br * 256 + ((g ^ br) << 2) + off] = acc[t][j];
            }
        }
    }
    __asm__ volatile("s_waitcnt lgkmcnt(0)" ::: "memory");   // wave-internal: writes drained

    // ---- pass-0 LDS reads ----
    f32x4 zt0[8];
    #pragma unroll
    for (int c = 0; c < 8; ++c) {
        const int gp = ((c << 3) + lo) ^ hi;
        zt0[c] = *(const f32x4*)&buf[hi * 256 + (gp << 2)];
    }

    // ---- issue pass-1 priors loads ----
    f32x4 pv1[8];
    {
        const float* pr = priors + (size_t)(r0 + 8 + hi) * DOUT;
        #pragma unroll
        for (int c = 0; c < 8; ++c)
            pv1[c] = __builtin_nontemporal_load((const f32x4*)(pr + (c << 5) + cb));
    }

    __asm__ volatile("s_waitcnt lgkmcnt(0)" ::: "memory");   // zt0 materialized (WAR safe)

    // ---- pass-1 LDS writes: rows 8..15 (lanes quad 2,3); acc dies here ----
    if (quad >= 2) {
        #pragma unroll
        for (int t = 0; t < 16; ++t) {
            const int col = (t << 4) + nl;
            const int g = col >> 2, off = col & 3;
            #pragma unroll
            for (int j = 0; j < 4; ++j) {
                const int br = ((quad & 1) << 2) + j;
                buf[br * 256 + ((g ^ br) << 2) + off] = acc[t][j];
            }
        }
    }

    // ---- pass-0 epilogue: BN + prior, sparsemax, NT store ----
    {
        const int rg = r0 + hi;
        #pragma unroll
        for (int c = 0; c < 8; ++c) {
            const f32x4 b2 = *(const f32x4*)(b2tab + (c << 5) + cb);
            #pragma unroll
            for (int j = 0; j < 4; ++j)
                zt0[c][j] = (zt0[c][j] + b2[j]) * pv0[c][j];
        }
        const float tau = michelot(zt0);
        #pragma unroll
        for (int c = 0; c < 8; ++c) {
            f32x4 o;
            #pragma unroll
            for (int j = 0; j < 4; ++j)
                o[j] = fmaxf(zt0[c][j] - tau, 0.0f);
            __builtin_nontemporal_store(o, (f32x4*)(out + (size_t)rg * DOUT + (c << 5) + cb));
        }
    }

    __asm__ volatile("s_waitcnt lgkmcnt(0)" ::: "memory");   // pass-1 writes drained

    // ---- pass-1 reads + epilogue ----
    {
        f32x4 zt1[8];
        #pragma unroll
        for (int c = 0; c < 8; ++c) {
            const int gp = ((c << 3) + lo) ^ hi;
            zt1[c] = *(const f32x4*)&buf[hi * 256 + (gp << 2)];
        }
        const int rg = r0 + 8 + hi;
        #pragma unroll
        for (int c = 0; c < 8; ++c) {
            const f32x4 b2 = *(const f32x4*)(b2tab + (c << 5) + cb);
            #pragma unroll
            for (int j = 0; j < 4; ++j)
                zt1[c][j] = (zt1[c][j] + b2[j]) * pv1[c][j];
        }
        const float tau = michelot(zt1);
        #pragma unroll
        for (int c = 0; c < 8; ++c) {
            f32x4 o;
            #pragma unroll
            for (int j = 0; j < 4; ++j)
                o[j] = fmaxf(zt1[c][j] - tau, 0.0f);
            __builtin_nontemporal_store(o, (f32x4*)(out + (size_t)rg * DOUT + (c << 5) + cb));
        }
    }
}

// ---------- fallback (round-1 kernel, proven correct) for tiny ws ----------
__global__ __launch_bounds__(256, 2)
void attentive_fallback(const float* __restrict__ A,
                        const float* __restrict__ priors,
                        const float* __restrict__ W,
                        const float* __restrict__ gamma,
                        const float* __restrict__ beta,
                        const float* __restrict__ mmean,
                        const float* __restrict__ mvar,
                        float* __restrict__ out)
{
    __shared__ _Float16 wlds[DIN * DOUT];
    const int tid = threadIdx.x;
    {
        const int n = tid;
        const float inv = gamma[n] / sqrtf(mvar[n] + 1e-3f);
        const int t = n >> 4, nl0 = n & 15;
        #pragma unroll 8
        for (int k = 0; k < DIN; ++k) {
            const int q = k >> 5, qd = (k >> 3) & 3, j = k & 7;
            const int idx = (((((t << 2) + q) << 6) + (qd << 4) + nl0) << 3) + j;
            wlds[idx] = (_Float16)(W[k * DOUT + n] * inv);
        }
    }
    __syncthreads();

    const int lane = tid & 63, wv = tid >> 6;
    const int nl = lane & 15, quad = lane >> 4;

    float b2r[16];
    #pragma unroll
    for (int t = 0; t < 16; ++t) {
        const int c = (t << 4) + nl;
        const float inv = gamma[c] / sqrtf(mvar[c] + 1e-3f);
        b2r[t] = beta[c] - mmean[c] * inv;
    }

    for (int chunk = blockIdx.x; chunk < NCHUNKS; chunk += gridDim.x) {
        const int r0 = chunk * 64 + wv * 16;
        f16x8 af[4];
        const float* arow = A + (size_t)(r0 + nl) * DIN + (quad << 3);
        #pragma unroll
        for (int q = 0; q < 4; ++q) {
            const f32x4 vlo = *(const f32x4*)(arow + (q << 5));
            const f32x4 vhi = *(const f32x4*)(arow + (q << 5) + 4);
            f16x8 v;
            v[0] = (_Float16)vlo[0]; v[1] = (_Float16)vlo[1];
            v[2] = (_Float16)vlo[2]; v[3] = (_Float16)vlo[3];
            v[4] = (_Float16)vhi[0]; v[5] = (_Float16)vhi[1];
            v[6] = (_Float16)vhi[2]; v[7] = (_Float16)vhi[3];
            af[q] = v;
        }
        f32x4 acc[16];
        #pragma unroll
        for (int t = 0; t < 16; ++t) {
            f32x4 c = {0.f, 0.f, 0.f, 0.f};
            #pragma unroll
            for (int q = 0; q < 4; ++q) {
                const f16x8 bf = *(const f16x8*)&wlds[((((t << 2) + q) << 6) + lane) << 3];
                c = __builtin_amdgcn_mfma_f32_16x16x32_f16(af[q], bf, c, 0, 0, 0);
            }
            acc[t] = c;
        }
        const int rb = r0 + (quad << 2);
        #pragma unroll
        for (int t = 0; t < 16; ++t) {
            const int c = (t << 4) + nl;
            #pragma unroll
            for (int j = 0; j < 4; ++j) {
                const float p = priors[(size_t)(rb + j) * DOUT + c];
                acc[t][j] = (acc[t][j] + b2r[t]) * p;
            }
        }
        float tau[4] = {-3.0e38f, -3.0e38f, -3.0e38f, -3.0e38f};
        int   kp[4]  = {-1, -1, -1, -1};
        for (int it = 0; it < 64; ++it) {
            float S[4] = {0.f, 0.f, 0.f, 0.f};
            int   K[4] = {0, 0, 0, 0};
            #pragma unroll
            for (int t = 0; t < 16; ++t) {
                #pragma unroll
                for (int j = 0; j < 4; ++j) {
                    const float z = acc[t][j];
                    const bool b = z > tau[j];
                    S[j] += b ? z : 0.0f;
                    K[j] += b ? 1 : 0;
                }
            }
            #pragma unroll
            for (int j = 0; j < 4; ++j) {
                S[j] += SWZ_F(S[j], 0x041F); K[j] += SWZ_I(K[j], 0x041F);
                S[j] += SWZ_F(S[j], 0x081F); K[j] += SWZ_I(K[j], 0x081F);
                S[j] += SWZ_F(S[j], 0x101F); K[j] += SWZ_I(K[j], 0x101F);
                S[j] += SWZ_F(S[j], 0x201F); K[j] += SWZ_I(K[j], 0x201F);
            }
            bool conv = true;
            #pragma unroll
            for (int j = 0; j < 4; ++j) {
                tau[j] = (S[j] - 1.0f) * __builtin_amdgcn_rcpf((float)K[j]);
                conv = conv && (K[j] == kp[j]);
                kp[j] = K[j];
            }
            if (__all(conv)) break;
        }
        #pragma unroll
        for (int t = 0; t < 16; ++t) {
            const int c = (t << 4) + nl;
            #pragma unroll
            for (int j = 0; j < 4; ++j)
                out[(size_t)(rb + j) * DOUT + c] = fmaxf(acc[t][j] - tau[j], 0.0f);
        }
    }
}

extern "C" void kernel_launch(void* const* d_in, const int* in_sizes, int n_in,
                              void* d_out, int out_size, void* d_ws, size_t ws_size,
                              hipStream_t stream) {
    const float* inputs = (const float*)d_in[0];
    const float* priors = (const float*)d_in[1];
    const float* W      = (const float*)d_in[2];
    const float* gam    = (const float*)d_in[3];
    const float* bet    = (const float*)d_in[4];
    const float* mmean  = (const float*)d_in[5];
    const float* mvar   = (const float*)d_in[6];
    float* outp = (float*)d_out;
    (void)in_sizes; (void)n_in; (void)out_size;

    if (ws_size >= (size_t)WS_NEED) {
        _Float16* wq    = (_Float16*)d_ws;
        float*    b2tab = (float*)((char*)d_ws + DIN * DOUT * 2);
        hipLaunchKernelGGL(prep_kernel, dim3(16), dim3(256), 0, stream,
                           W, gam, bet, mmean, mvar, wq, b2tab);
        hipLaunchKernelGGL(attentive_main, dim3(NCHUNKS), dim3(256), 0, stream,
                           inputs, priors, wq, b2tab, outp);
    } else {
        hipLaunchKernelGGL(attentive_fallback, dim3(1024), dim3(256), 0, stream,
                           inputs, priors, W, gam, bet, mmean, mvar, outp);
    }
}